// Round 20
// baseline (126.287 us; speedup 1.0000x reference)
//
#include <hip/hip_runtime.h>

#define BB 8
#define NN 2048
#define HH 4
#define EE 64
#define MAXJ 128
#define NEG 0.2f
#define NBLK 256

static constexpr int OFF_PART = 64;                      // [256][8][64] partials
static constexpr int OFF_S    = OFF_PART + NBLK * BB * EE; // [8]
static constexpr int OFF_BAR  = OFF_S + 16;              // int cnt, gen

__global__ void k_init(float* ws) {
    if (threadIdx.x == 0) {
        ((int*)(ws + OFF_BAR))[0] = 0;   // cnt
        ((int*)(ws + OFF_BAR))[1] = 0;   // gen
    }
}

__device__ __forceinline__ void gbar(int* cnt, int* gen) {
    __syncthreads();
    if (threadIdx.x == 0) {
        int g = atomicAdd(gen, 0);
        __threadfence();
        if (atomicAdd(cnt, 1) == NBLK - 1) {
            atomicExch(cnt, 0);
            __threadfence();
            atomicAdd(gen, 1);
        } else {
            int spins = 0;
            while (atomicAdd(gen, 0) == g && spins < (1 << 22)) {
                __builtin_amdgcn_s_sleep(2);
                ++spins;
            }
        }
        __threadfence();
    }
    __syncthreads();
}

__global__ __launch_bounds__(256) void mega(
    const int* __restrict__ adj, const float* __restrict__ state,
    const float* __restrict__ strucEmb, const float* __restrict__ Ws,
    const float* __restrict__ W_gat, const float* __restrict__ att,
    const float* __restrict__ Wst,
    const float* __restrict__ l1w, const float* __restrict__ l1b,
    const float* __restrict__ l2w, const float* __restrict__ l2b,
    const float* __restrict__ l3w, const float* __restrict__ l3b,
    float* __restrict__ ws, float* __restrict__ out)
{
    __shared__ float s_wgw[HH * EE];       // 0.25 * WgWst[h][f]
    __shared__ float s_cs[HH], s_ct[HH];
    __shared__ int   s_jq[4][MAXJ];
    __shared__ int   s_c[4];
    __shared__ int   s_jl[MAXJ];
    __shared__ int   s_cnt;
    __shared__ float s_y[BB * MAXJ];
    __shared__ float s_satt[8][4 * BB];    // [r][b*4+h]
    __shared__ float s_sws[8][EE];
    __shared__ float s_acc[2 * 256];       // se partial [b][f]
    __shared__ float s_se[EE];
    __shared__ float s_S[BB];

    const int t = threadIdx.x;
    const int w = t >> 6, lane = t & 63;
    int* bar = (int*)(ws + OFF_BAR);

    // ---- prologue: wgw (0.25-folded), c_src/c_tgt ----
    {
        int h = t >> 6, f = t & 63;
        float acc = 0.f;
        for (int e = 0; e < EE; ++e) acc += W_gat[h * EE + e] * Wst[f * EE + e];
        s_wgw[t] = 0.25f * acc;
        if (t < 2 * HH) {
            int hh = t & 3;
            const float* wgh = W_gat + hh * EE;
            const float* av  = att + hh * 2 * EE + (t >= HH ? EE : 0);
            float a2 = 0.f;
            for (int e = 0; e < EE; ++e) a2 += wgh[e] * av[e];
            if (t < HH) s_cs[hh] = a2; else s_ct[hh] = a2;
        }
        s_acc[t] = 0.f; s_acc[256 + t] = 0.f;
    }
    __syncthreads();

    // ---- P1: 8 rows per block (stride NBLK) ----
    for (int r = 0; r < 8; ++r) {
        const int i = blockIdx.x + r * NBLK;
        {   // 4-wave quarter-row scan (adj int32, verified r11/r13)
            const int* a = adj + (size_t)i * NN + w * (NN / 4);
            int lc = 0;
            for (int it = 0; it < NN / 256; ++it) {
                int j = it * 64 + lane;
                bool edge = (a[j] == 0);
                unsigned long long m = __ballot(edge);
                if (edge) {
                    int pos = lc + __popcll(m & ((1ull << lane) - 1ull));
                    if (pos < MAXJ) s_jq[w][pos] = w * (NN / 4) + j;
                }
                lc += __popcll(m);
            }
            if (lane == 0) s_c[w] = lc > MAXJ ? MAXJ : lc;
        }
        __syncthreads();
        {   // deterministic merge
            int base = 0;
            for (int q = 0; q < w; ++q) base += s_c[q];
            int cw = s_c[w];
            for (int k = lane; k < cw; k += 64) {
                int pos = base + k;
                if (pos < MAXJ) s_jl[pos] = s_jq[w][k];
            }
            if (t == 0) {
                int tot = s_c[0] + s_c[1] + s_c[2] + s_c[3];
                s_cnt = tot > MAXJ ? MAXJ : tot;
            }
        }
        __syncthreads();
        const int cnt = s_cnt;

        if (w == 0) {   // SWS row
            float v = strucEmb[(size_t)i * EE + lane];
            float acc = 0.f;
            for (int e = 0; e < EE; ++e) acc += __shfl(v, e) * Ws[lane * EE + e];
            s_sws[r][lane] = acc;
        } else {        // stage neighbor values
            for (int x = t - 64; x < BB * MAXJ; x += 192) {
                int k = x & (MAXJ - 1);
                if (k < cnt) s_y[x] = state[(x >> 7) * NN + s_jl[k]];
            }
        }
        __syncthreads();

        {   // softmax: 32 groups x 8 lanes = (b,h)
            int g = t >> 3, k0 = t & 7, b = g >> 2, h = g & 3;
            const float* yb = s_y + b * MAXJ;
            float ct = s_ct[h];
            float si = state[b * NN + i] * s_cs[h];
            float mmax = -1e30f;
            for (int k = k0; k < cnt; k += 8) {
                float e = si + ct * yb[k]; e = e > 0.f ? e : NEG * e;
                mmax = fmaxf(mmax, e);
            }
            for (int o = 4; o; o >>= 1) mmax = fmaxf(mmax, __shfl_xor(mmax, o, 8));
            float den = 0.f, num = 0.f;
            for (int k = k0; k < cnt; k += 8) {
                float y = yb[k];
                float e = si + ct * y; e = e > 0.f ? e : NEG * e;
                float p = expf(e - mmax);
                den += p; num += p * y;
            }
            for (int o = 4; o; o >>= 1) { den += __shfl_xor(den, o, 8); num += __shfl_xor(num, o, 8); }
            if (k0 == 0) s_satt[r][g] = num / den;
        }
        __syncthreads();

        // se accumulate: x[b][f] = sws[f] + sum_h satt*wgw ; relu; acc +=
        for (int q = 0; q < 2; ++q) {
            int idx = q * 256 + t, b = idx >> 6, f = idx & 63;
            float x = s_sws[r][f];
            for (int h = 0; h < HH; ++h)
                x += s_satt[r][b * 4 + h] * s_wgw[h * EE + f];
            s_acc[idx] += fmaxf(x, 0.f);
        }
        __syncthreads();
    }
    // publish partials
    ws[OFF_PART + (size_t)blockIdx.x * 512 + t]       = s_acc[t];
    ws[OFF_PART + (size_t)blockIdx.x * 512 + 256 + t] = s_acc[256 + t];

    gbar(bar, bar + 1);

    // ---- P2: blocks 0..7 compute S[b] ----
    if (blockIdx.x < BB) {
        int b = blockIdx.x;
        if (t < EE) {
            float se = 0.f;
            for (int c = 0; c < NBLK; ++c)
                se += ws[OFF_PART + (size_t)c * 512 + b * EE + t];
            s_se[t] = se;
        }
        __syncthreads();
        if (t < EE) {
            float bs = l1b[t];
            for (int f = 0; f < EE; ++f) bs += s_se[f] * l1w[t * EE + f];
            float rr = fmaxf(bs, 0.f) * l3w[t];
            for (int o = 32; o; o >>= 1) rr += __shfl_xor(rr, o);
            if (t == 0) ws[OFF_S + b] = rr + l3b[0];
        }
    }

    gbar(bar, bar + 1);

    // ---- P3: outputs for this block's 8 rows ----
    if (t < BB) s_S[t] = ws[OFF_S + t];
    __syncthreads();
    for (int r = 0; r < 8; ++r) {
        const int i = blockIdx.x + r * NBLK;
        for (int p = 0; p < 2; ++p) {
            int b = p * 4 + w;
            float xv = s_sws[r][lane];
            for (int h = 0; h < HH; ++h)
                xv += s_satt[r][b * 4 + h] * s_wgw[h * EE + lane];
            xv = fmaxf(xv, 0.f);
            float acc = l2b[lane];
            for (int f = 0; f < EE; ++f) acc += __shfl(xv, f) * l2w[lane * EE + f];
            float rr = fmaxf(acc, 0.f) * l3w[EE + lane];
            for (int o = 32; o; o >>= 1) rr += __shfl_xor(rr, o);
            if (lane == 0) out[(size_t)b * NN + i] = s_S[b] + rr;
        }
    }
}

extern "C" void kernel_launch(void* const* d_in, const int* in_sizes, int n_in,
                              void* d_out, int out_size, void* d_ws, size_t ws_size,
                              hipStream_t stream) {
    const float* state    = (const float*)d_in[0];
    const float* strucEmb = (const float*)d_in[1];
    const int*   adj      = (const int*)d_in[2];   // int32 {0,1}, verified r11/r13
    const float* W_gat    = (const float*)d_in[3];
    const float* att      = (const float*)d_in[4];
    const float* Ws       = (const float*)d_in[5];
    const float* Wst      = (const float*)d_in[6];
    const float* lin1_w   = (const float*)d_in[7];
    const float* lin1_b   = (const float*)d_in[8];
    const float* lin2_w   = (const float*)d_in[9];
    const float* lin2_b   = (const float*)d_in[10];
    const float* lin3_w   = (const float*)d_in[11];
    const float* lin3_b   = (const float*)d_in[12];
    float* ws = (float*)d_ws;
    float* out = (float*)d_out;   // f32 output, verified r13

    k_init<<<dim3(1), dim3(64), 0, stream>>>(ws);
    mega<<<dim3(NBLK), dim3(256), 0, stream>>>(
        adj, state, strucEmb, Ws, W_gat, att, Wst,
        lin1_w, lin1_b, lin2_w, lin2_b, lin3_w, lin3_b, ws, out);
}

// Round 21
// 54.063 us; speedup vs baseline: 2.3359x; 2.3359x over previous
//
#include <hip/hip_runtime.h>

#define BB 8
#define NN 2048
#define HH 4
#define EE 64
#define MAXJ 128
#define NEG 0.2f
#define NCHUNK 32

static constexpr int OFF_CSRC  = 0;                          // [4]
static constexpr int OFF_CTGT  = 4;                          // [4]
static constexpr int OFF_WGWST = 8;                          // [4][64]
static constexpr int OFF_S     = 264;                        // [8]
static constexpr int OFF_SWS   = 288;                        // float[N*E]
static constexpr int OFF_SATT  = OFF_SWS + NN * EE;          // float[B*H*N]
static constexpr int OFF_PART  = OFF_SATT + BB * HH * NN;    // float[NCHUNK*B*E]

// ---- prep: c_src/c_tgt + WgWst[h][f] ----
__global__ __launch_bounds__(256) void k_prep(const float* __restrict__ W_gat,
                                              const float* __restrict__ att,
                                              const float* __restrict__ Wst,
                                              float* __restrict__ ws) {
    __shared__ float wg[HH * EE];
    int t = threadIdx.x; // 256
    wg[t] = W_gat[t];
    __syncthreads();
    if (t < HH) {
        float cs = 0.f, ct = 0.f;
        for (int e = 0; e < EE; ++e) {
            cs += wg[t * EE + e] * att[t * 2 * EE + e];
            ct += wg[t * EE + e] * att[t * 2 * EE + EE + e];
        }
        ws[OFF_CSRC + t] = cs;
        ws[OFF_CTGT + t] = ct;
    }
    int h = t >> 6, f = t & 63;
    float acc = 0.f;
    for (int e = 0; e < EE; ++e) acc += wg[h * EE + e] * Wst[f * EE + e];
    ws[OFF_WGWST + t] = acc; // WgWst[h][f]
}

// ---- fused per-row: adj scan + SWS row (LDS-transposed Ws) + sparse softmax ----
__global__ __launch_bounds__(256) void k_fsatt(const int* __restrict__ adj,
                                               const float* __restrict__ state,
                                               const float* __restrict__ strucEmb,
                                               const float* __restrict__ Ws,
                                               float* __restrict__ ws) {
    __shared__ float s_wsT[EE * 65];   // s_wsT[e*65+f] = Ws[f][e]
    __shared__ int   s_jl[MAXJ];
    __shared__ int   s_cnt;
    __shared__ float s_y[BB * MAXJ];
    const int i = blockIdx.x;
    const int t = threadIdx.x;
    const int w = t >> 6, lane = t & 63;

    if (w == 0) {
        // wave 0: deterministic neighbor-list compaction of row i (adj int32, r11/r13)
        const int* a = adj + (size_t)i * NN;
        int cnt = 0;
        for (int it = 0; it < NN / 64; ++it) {
            int j = it * 64 + lane;
            bool edge = (a[j] == 0);
            unsigned long long m = __ballot(edge);
            if (edge) {
                int pos = cnt + __popcll(m & ((1ull << lane) - 1ull));
                if (pos < MAXJ) s_jl[pos] = j;
            }
            cnt += __popcll(m);
        }
        if (lane == 0) s_cnt = cnt > MAXJ ? MAXJ : cnt;
    } else if (w == 1) {
        // wave 1 (concurrent): stage Ws transposed, coalesced reads
        for (int it = 0; it < EE; ++it)
            s_wsT[lane * 65 + it] = Ws[it * EE + lane];  // [f=it][e=lane] -> [e][f]
    }
    __syncthreads();
    const int cnt = s_cnt;

    if (w == 0) {
        // SWS[i][f=lane] from LDS (banks (e+lane)%32, conflict-free)
        float v = strucEmb[(size_t)i * EE + lane];
        float acc = 0.f;
        for (int e = 0; e < EE; ++e)
            acc += __shfl(v, e) * s_wsT[e * 65 + lane];
        ws[OFF_SWS + i * EE + lane] = acc;
    } else {
        // waves 1-3: stage neighbor state values for all 8 batches
        for (int x = t - 64; x < BB * MAXJ; x += 192) {
            int k = x & (MAXJ - 1);
            if (k < cnt) s_y[x] = state[(x >> 7) * NN + s_jl[k]];
        }
    }
    __syncthreads();

    // 32 groups x 8 lanes: group = (b,h)
    int g = t >> 3, k0 = t & 7, b = g >> 2, h = g & 3;
    const float* yb = s_y + b * MAXJ;
    float ct = ws[OFF_CTGT + h];
    float si = state[b * NN + i] * ws[OFF_CSRC + h];
    float mmax = -1e30f;
    for (int k = k0; k < cnt; k += 8) {
        float e = si + ct * yb[k]; e = e > 0.f ? e : NEG * e;
        mmax = fmaxf(mmax, e);
    }
    for (int o = 4; o; o >>= 1) mmax = fmaxf(mmax, __shfl_xor(mmax, o, 8));
    float den = 0.f, num = 0.f;
    for (int k = k0; k < cnt; k += 8) {
        float y = yb[k];
        float e = si + ct * y; e = e > 0.f ? e : NEG * e;
        float p = expf(e - mmax);
        den += p; num += p * y;
    }
    for (int o = 4; o; o >>= 1) { den += __shfl_xor(den, o, 8); num += __shfl_xor(num, o, 8); }
    if (k0 == 0) ws[OFF_SATT + (b * HH + h) * NN + i] = num / den;
}

// ---- se partials: block (chunk,b) sums relu(x[b,i,f]) over 64 rows ----
__global__ void k_se(float* __restrict__ ws) {
    int b = blockIdx.x & 7, chunk = blockIdx.x >> 3;
    int t = threadIdx.x; // 256
    int f = t & 63, sl = t >> 6;
    float wgw[HH];
    for (int h = 0; h < HH; ++h) wgw[h] = 0.25f * ws[OFF_WGWST + h * EE + f];
    float acc = 0.f;
    int i0 = chunk * (NN / NCHUNK);
    for (int i = i0 + sl; i < i0 + NN / NCHUNK; i += 4) {
        float v = ws[OFF_SWS + i * EE + f];
        for (int h = 0; h < HH; ++h)
            v += ws[OFF_SATT + (b * HH + h) * NN + i] * wgw[h];
        acc += fmaxf(v, 0.f);
    }
    __shared__ float red[256];
    red[t] = acc;
    __syncthreads();
    if (t < EE)
        ws[OFF_PART + (size_t)blockIdx.x * EE + t] =
            red[t] + red[t + 64] + red[t + 128] + red[t + 192];
}

// ---- S[b] = relu(se @ l1w.T + l1b) . l3w[:64] + l3b (LDS-transposed l1w) ----
__global__ void k_S(const float* __restrict__ lin1_w, const float* __restrict__ lin1_b,
                    const float* __restrict__ lin3_w, const float* __restrict__ lin3_b,
                    float* __restrict__ ws) {
    int b = blockIdx.x;
    int t = threadIdx.x; // 64
    __shared__ float s_l1T[EE * 65];   // s_l1T[f2*65+o] = lin1_w[o][f2]
    __shared__ float s_se[EE];
    for (int it = 0; it < EE; ++it)
        s_l1T[t * 65 + it] = lin1_w[it * EE + t];   // coalesced read row it
    float se = 0.f;
    for (int c = 0; c < NCHUNK; ++c)
        se += ws[OFF_PART + (size_t)(c * BB + b) * EE + t];
    s_se[t] = se;
    __syncthreads();
    float bs = lin1_b[t];
    for (int f2 = 0; f2 < EE; ++f2) bs += s_se[f2] * s_l1T[f2 * 65 + t];
    float r = fmaxf(bs, 0.f) * lin3_w[t];
    for (int o = 32; o; o >>= 1) r += __shfl_xor(r, o);
    if (t == 0) ws[OFF_S + b] = r + lin3_b[0];
}

// ---- out[b,i] = S[b] + sum_f relu(beta_action)[f]*l3w[64+f] (LDS-transposed l2w) ----
__global__ __launch_bounds__(256) void v13_out(const float* __restrict__ lin2_w,
                                               const float* __restrict__ lin2_b,
                                               const float* __restrict__ lin3_w,
                                               const float* __restrict__ ws,
                                               float* __restrict__ out) {
    __shared__ float s_l2T[EE * 65];   // s_l2T[f*65+fp] = lin2_w[fp][f]
    const int t = threadIdx.x;
    for (int k = t; k < EE * EE; k += 256) {
        int fp = k >> 6, f = k & 63;
        s_l2T[f * 65 + fp] = lin2_w[k];   // coalesced read
    }
    __syncthreads();
    int wave = blockIdx.x * 4 + (t >> 6);
    int lane = t & 63;
    int i = wave >> 3, b = wave & 7;
    float xv = ws[OFF_SWS + i * EE + lane];
    for (int h = 0; h < HH; ++h)
        xv += 0.25f * ws[OFF_SATT + (b * HH + h) * NN + i] * ws[OFF_WGWST + h * EE + lane];
    xv = fmaxf(xv, 0.f);
    float acc = lin2_b[lane];
    for (int f = 0; f < EE; ++f) acc += __shfl(xv, f) * s_l2T[f * 65 + lane];
    float r = fmaxf(acc, 0.f) * lin3_w[EE + lane];
    for (int o = 32; o; o >>= 1) r += __shfl_xor(r, o);
    if (lane == 0) out[(size_t)b * NN + i] = ws[OFF_S + b] + r;
}

extern "C" void kernel_launch(void* const* d_in, const int* in_sizes, int n_in,
                              void* d_out, int out_size, void* d_ws, size_t ws_size,
                              hipStream_t stream) {
    const float* state    = (const float*)d_in[0];
    const float* strucEmb = (const float*)d_in[1];
    const int*   adj      = (const int*)d_in[2];   // int32 {0,1}, verified r11/r13
    const float* W_gat    = (const float*)d_in[3];
    const float* att      = (const float*)d_in[4];
    const float* Ws       = (const float*)d_in[5];
    const float* Wst      = (const float*)d_in[6];
    const float* lin1_w   = (const float*)d_in[7];
    const float* lin1_b   = (const float*)d_in[8];
    const float* lin2_w   = (const float*)d_in[9];
    const float* lin2_b   = (const float*)d_in[10];
    const float* lin3_w   = (const float*)d_in[11];
    const float* lin3_b   = (const float*)d_in[12];
    float* ws = (float*)d_ws;
    float* out = (float*)d_out;   // f32 output, verified r13

    k_prep <<<dim3(1),           dim3(256), 0, stream>>>(W_gat, att, Wst, ws);
    k_fsatt<<<dim3(NN),          dim3(256), 0, stream>>>(adj, state, strucEmb, Ws, ws);
    k_se   <<<dim3(NCHUNK * BB), dim3(256), 0, stream>>>(ws);
    k_S    <<<dim3(BB),          dim3(64),  0, stream>>>(lin1_w, lin1_b, lin3_w, lin3_b, ws);
    v13_out<<<dim3(NN * BB / 4), dim3(256), 0, stream>>>(lin2_w, lin2_b, lin3_w, ws, out);
}